// Round 5
// baseline (8936.575 us; speedup 1.0000x reference)
//
#include <hip/hip_runtime.h>

// Problem dims (fp32 in / fp32 out)
#define B_   64
#define T_   512
#define DIN_ 256
#define H_   512
#define DOUT_ 128

typedef _Float16 f16x8 __attribute__((ext_vector_type(8)));
typedef float f32x4  __attribute__((ext_vector_type(4)));
typedef _Float16 half2v __attribute__((ext_vector_type(2)));

// ---------------------------------------------------------------------------
// dot of 8 f16 pairs (w,h packed as uint4) accumulated into fp32
__device__ __forceinline__ float dot8(uint4 w, uint4 h, float s) {
#if __has_builtin(__builtin_amdgcn_fdot2)
  s = __builtin_amdgcn_fdot2(__builtin_bit_cast(half2v, w.x), __builtin_bit_cast(half2v, h.x), s, false);
  s = __builtin_amdgcn_fdot2(__builtin_bit_cast(half2v, w.y), __builtin_bit_cast(half2v, h.y), s, false);
  s = __builtin_amdgcn_fdot2(__builtin_bit_cast(half2v, w.z), __builtin_bit_cast(half2v, h.z), s, false);
  s = __builtin_amdgcn_fdot2(__builtin_bit_cast(half2v, w.w), __builtin_bit_cast(half2v, h.w), s, false);
#else
  const half2v* wp = (const half2v*)&w;
  const half2v* hp = (const half2v*)&h;
#pragma unroll
  for (int q = 0; q < 4; ++q) {
    s += (float)wp[q][0] * (float)hp[q][0] + (float)wp[q][1] * (float)hp[q][1];
  }
#endif
  return s;
}

// fast branchless tanh: tanh(x) = sign(x) * (1 - 2/(e^{2|x|}+1)); |err| ~1e-6
__device__ __forceinline__ float fast_tanh(float x) {
  float a = fabsf(x);
  float e = __expf(2.f * a);
  float r = 1.f - 2.f / (e + 1.f);
  return copysignf(r, x);
}

// opaque pin: forces v's components into arch VGPRs, non-rematerializable
__device__ __forceinline__ void pin4(uint4& v) {
  asm volatile("" : "+v"(v.x), "+v"(v.y), "+v"(v.z), "+v"(v.w));
}

// ---------------------------------------------------------------------------
// Generic fp32 -> f16 conversion (memory-bound, one-shot prep)
__global__ void cvt_f32_f16(const float* __restrict__ in, _Float16* __restrict__ out, int n) {
  int idx = blockIdx.x * 256 + threadIdx.x;
  if (idx < n) out[idx] = (_Float16)in[idx];
}

// ---------------------------------------------------------------------------
// Prep: convert W_hh (fp32, row-major HxH) into the scan's register-fill layout:
//   chunk index c = ((q*2 + u)*32 + i)*256 + r  holds  W[q*256+r][(u*32+i)*8 .. +8)
// (q = row half, u = k half, i = k-chunk within half, r = row within half)
// Thread (r,u) of scan WG (b,q) then loads chunks i=0..31 at stride 256 — coalesced.
__global__ void prep_w(const float* __restrict__ w0, const float* __restrict__ w1,
                       _Float16* __restrict__ o0, _Float16* __restrict__ o1) {
  int idx = blockIdx.x * 256 + threadIdx.x;        // 0 .. 65535 (two matrices)
  const float* src = (idx < 32768) ? w0 : w1;
  _Float16* dst = (idx < 32768) ? o0 : o1;
  int c = idx & 32767;
  int r = c & 255;
  int rest = c >> 8;          // 0..127
  int i = rest & 31;
  int uu = rest >> 5;         // q*2 + u
  int row = (uu >> 1) * 256 + r;
  int kc  = (uu & 1) * 32 + i;
#pragma unroll
  for (int e = 0; e < 8; ++e)
    dst[(size_t)c * 8 + e] = (_Float16)src[row * 512 + kc * 8 + e];
}

// ---------------------------------------------------------------------------
// GEMM: out[m,n] = sum_k X[m,k]*W[n,k] + bias1[n] + bias2[n], written as f16.
// 128x128 tile / 256 threads / 4 waves (2x2 of 64x64), BK=32, m97-style
// global_load_lds(16B) staging, 16x16x32 f16 MFMA.  (unchanged from r3 — ~40 us)
__global__ __launch_bounds__(256)
void gemm_xproj(const _Float16* __restrict__ X,
                const _Float16* __restrict__ W,
                const float* __restrict__ bias1,
                const float* __restrict__ bias2,
                _Float16* __restrict__ out, int K) {
  __shared__ __align__(16) _Float16 As[128 * 32];
  __shared__ __align__(16) _Float16 Bs[128 * 32];
  const int tid  = threadIdx.x;
  const int wave = tid >> 6;
  const int lane = tid & 63;
  const int wr = wave >> 1, wc = wave & 1;
  const int m0 = blockIdx.x * 128, n0 = blockIdx.y * 128;
  const int fr = lane & 15;
  const int fk = (lane >> 4) * 8;
  const int cA = (lane & 3) * 8;
  const int rsub = lane >> 2;

  f32x4 acc[4][4];
#pragma unroll
  for (int a = 0; a < 4; ++a)
#pragma unroll
    for (int b = 0; b < 4; ++b)
      acc[a][b] = (f32x4){0.f, 0.f, 0.f, 0.f};

  for (int k0 = 0; k0 < K; k0 += 32) {
    __syncthreads();
#pragma unroll
    for (int q = 0; q < 2; ++q) {
      int p = wave * 2 + q;
      int r = p * 16 + rsub;
      const _Float16* gA = X + (size_t)(m0 + r) * K + (k0 + cA);
      const _Float16* gB = W + (size_t)(n0 + r) * K + (k0 + cA);
      __builtin_amdgcn_global_load_lds(
          (const __attribute__((address_space(1))) void*)gA,
          (__attribute__((address_space(3))) void*)((char*)As + p * 1024), 16, 0, 0);
      __builtin_amdgcn_global_load_lds(
          (const __attribute__((address_space(1))) void*)gB,
          (__attribute__((address_space(3))) void*)((char*)Bs + p * 1024), 16, 0, 0);
    }
    __syncthreads();

    f16x8 af[4], bfr[4];
#pragma unroll
    for (int mt = 0; mt < 4; ++mt)
      af[mt] = *(const f16x8*)&As[(wr * 64 + mt * 16 + fr) * 32 + fk];
#pragma unroll
    for (int nt = 0; nt < 4; ++nt)
      bfr[nt] = *(const f16x8*)&Bs[(wc * 64 + nt * 16 + fr) * 32 + fk];
#pragma unroll
    for (int mt = 0; mt < 4; ++mt)
#pragma unroll
      for (int nt = 0; nt < 4; ++nt)
        acc[mt][nt] = __builtin_amdgcn_mfma_f32_16x16x32_f16(af[mt], bfr[nt], acc[mt][nt], 0, 0, 0);
  }

  const int col = lane & 15, rq = lane >> 4;
#pragma unroll
  for (int nt = 0; nt < 4; ++nt) {
    int n = n0 + wc * 64 + nt * 16 + col;
    float bias = bias1[n] + bias2[n];
#pragma unroll
    for (int mt = 0; mt < 4; ++mt) {
      int mbase = m0 + wr * 64 + mt * 16 + rq * 4;
#pragma unroll
      for (int r = 0; r < 4; ++r)
        out[(size_t)(mbase + r) * H_ + n] = (_Float16)(acc[mt][nt][r] + bias);
    }
  }
}

// ---------------------------------------------------------------------------
// Recurrent scan, round-5 structure: 2 WGs per batch element (grid = 128),
// WG g: q = g>>6 (row half), b = g&63. 512 threads = 256 rows x 2 k-halves;
// thread (r,u) holds W[q*256+r][u*256 .. u*256+255] = 32 uint4 = 128 VGPRs —
// the ENTIRE W slice is register-resident (r2-r4 lesson: W re-fetch from
// L2/LDS/scratch was the wall). Per step: 128 fdot2/thread (512 issue-cyc/SIMD),
// k-halves reduced via LDS, then the two WGs exchange 256-row h halves through
// global memory with agent-scope atomics + a flag handshake (double-buffered;
// g = q*64+b keeps partners on one XCD under %8 round-robin — perf-only).
__global__ __launch_bounds__(512, 2)
void rnn_scan(const uint4* __restrict__ Wq, const _Float16* __restrict__ xproj,
              _Float16* __restrict__ seq, float* __restrict__ hlast,
              unsigned int* __restrict__ hglob,   // [2][64][512] exchange (f16 in low bits)
              unsigned int* __restrict__ flags,   // [128], pre-zeroed
              int mode) {
  __shared__ _Float16 hb[2][512];
  __shared__ float psum[256];
  const int g = blockIdx.x;
  const int q = g >> 6, b = g & 63;
  const int tid = threadIdx.x;
  const int r = tid & 255, u = tid >> 8;

  // W slice -> 128 VGPRs (coalesced: lane stride = 16B)
  uint4 w[32];
  const uint4* wp = Wq + (size_t)(q * 2 + u) * 32 * 256 + r;
#pragma unroll
  for (int i = 0; i < 32; ++i) w[i] = wp[(size_t)i * 256];
#pragma unroll
  for (int i = 0; i < 32; ++i) pin4(w[i]);

  hb[0][tid] = (_Float16)0.f;
  hb[1][tid] = (_Float16)0.f;
  __syncthreads();

  unsigned int* flag_own = flags + g;
  unsigned int* flag_par = flags + ((1 - q) << 6) + b;
  const _Float16* xp = xproj + (size_t)b * (T_ * H_) + q * 256 + r;
  unsigned int* hg_b = hglob + b * 512;
  int cur = 0;
  for (int t = 0; t < T_; ++t) {
    const uint4* hbu = (const uint4*)hb[cur];
    float sa = 0.f, sb = 0.f, sc = 0.f, sd = 0.f;   // 4 chains
#pragma unroll
    for (int i = 0; i < 32; i += 4) {
      sa = dot8(w[i],     hbu[u * 32 + i],     sa);
      sb = dot8(w[i + 1], hbu[u * 32 + i + 1], sb);
      sc = dot8(w[i + 2], hbu[u * 32 + i + 2], sc);
      sd = dot8(w[i + 3], hbu[u * 32 + i + 3], sd);
    }
    float s = (sa + sb) + (sc + sd);
    if (u == 1) psum[r] = s;
    __syncthreads();                                // A: k-half partials visible

    unsigned int* hg = hg_b + (t & 1) * (64 * 512);
    if (u == 0) {
      float hn = fast_tanh(s + psum[r] + (float)xp[(size_t)t * H_]);
      _Float16 h16 = (_Float16)hn;
      hb[cur ^ 1][q * 256 + r] = h16;
      __hip_atomic_store(hg + q * 256 + r,
                         (unsigned int)__builtin_bit_cast(unsigned short, h16),
                         __ATOMIC_RELAXED, __HIP_MEMORY_SCOPE_AGENT);
      if (mode == 0)
        seq[(size_t)b * (T_ * H_) + (size_t)t * H_ + q * 256 + r] = h16;
      else if (t == T_ - 1)
        hlast[b * H_ + q * 256 + r] = hn;
    }
    if (t == T_ - 1) break;                         // no exchange needed after last step
    __syncthreads();                                // B: vmcnt(0) drain -> h stores visible
    if (tid == 0)
      __hip_atomic_store(flag_own, (unsigned int)(t + 1),
                         __ATOMIC_RELEASE, __HIP_MEMORY_SCOPE_AGENT);
    if (u == 1) {
      while (__hip_atomic_load(flag_par, __ATOMIC_ACQUIRE,
                               __HIP_MEMORY_SCOPE_AGENT) <= (unsigned int)t) {}
      unsigned int pv = __hip_atomic_load(hg + (1 - q) * 256 + r,
                                          __ATOMIC_RELAXED, __HIP_MEMORY_SCOPE_AGENT);
      hb[cur ^ 1][(1 - q) * 256 + r] =
          __builtin_bit_cast(_Float16, (unsigned short)(pv & 0xFFFFu));
    }
    __syncthreads();                                // C: hb[cur^1] complete
    cur ^= 1;
  }
}

// ---------------------------------------------------------------------------
// Final FC: out[b,o] = h2[b,:] . w_fc[o,:] + b_fc[o]   (64 x 128, tiny, pure fp32)
__global__ void fc_kernel(const float* __restrict__ h2,
                          const float* __restrict__ wfc,
                          const float* __restrict__ bfc,
                          float* __restrict__ out) {
  int b = blockIdx.x, o = threadIdx.x;
  float s = bfc[o];
  const float* hv = h2 + b * H_;
  const float* wr = wfc + (size_t)o * H_;
#pragma unroll 8
  for (int k = 0; k < H_; ++k) s += hv[k] * wr[k];
  out[b * DOUT_ + o] = s;
}

// ---------------------------------------------------------------------------
extern "C" void kernel_launch(void* const* d_in, const int* in_sizes, int n_in,
                              void* d_out, int out_size, void* d_ws, size_t ws_size,
                              hipStream_t stream) {
  const float* x     = (const float*)d_in[0];
  const float* w_ih0 = (const float*)d_in[1];
  const float* w_hh0 = (const float*)d_in[2];
  const float* b_ih0 = (const float*)d_in[3];
  const float* b_hh0 = (const float*)d_in[4];
  const float* w_ih1 = (const float*)d_in[5];
  const float* w_hh1 = (const float*)d_in[6];
  const float* b_ih1 = (const float*)d_in[7];
  const float* b_hh1 = (const float*)d_in[8];
  const float* w_fc  = (const float*)d_in[9];
  const float* b_fc  = (const float*)d_in[10];

  char* ws = (char*)d_ws;
  _Float16* Ws0       = (_Float16*)(ws + 0);          // 512 KB  (w_hh0 scan layout)
  _Float16* Ws1       = (_Float16*)(ws + 524288);     // 512 KB  (w_hh1 scan layout)
  _Float16* Wih0      = (_Float16*)(ws + 1048576);    // 256 KB  (w_ih0 f16)
  _Float16* Wih1      = (_Float16*)(ws + 1310720);    // 512 KB  (w_ih1 f16)
  float*    h2        = (float*)   (ws + 2097152);    // 128 KB  (final hidden, fp32)
  unsigned int* hglob = (unsigned int*)(ws + 2359296);// 256 KB  h exchange [2][64][512]
  unsigned int* flg0  = (unsigned int*)(ws + 2621440);// 512 B   scan-0 flags
  unsigned int* flg1  = (unsigned int*)(ws + 2621952);// 512 B   scan-1 flags
  _Float16* xproj     = (_Float16*)(ws + 4194304);    // 32 MB   (32768x512 f16)
  _Float16* xf16      = (_Float16*)(ws + 37748736);   // x as f16, then dead...
  _Float16* h1seq     = (_Float16*)(ws + 37748736);   // ...h1 sequence f16 (32 MB)

  // 0) zero the handshake flags (re-poisoned to 0xAA before every launch)
  hipMemsetAsync(flg0, 0, 1024, stream);              // covers flg0 + flg1

  // 1) one-shot conversions to f16
  cvt_f32_f16<<<32768, 256, 0, stream>>>(x, xf16, B_ * T_ * DIN_);
  cvt_f32_f16<<<512,   256, 0, stream>>>(w_ih0, Wih0, H_ * DIN_);
  cvt_f32_f16<<<1024,  256, 0, stream>>>(w_ih1, Wih1, H_ * H_);
  prep_w<<<256, 256, 0, stream>>>(w_hh0, w_hh1, Ws0, Ws1);

  // 2) xproj0 = x @ w_ih0^T + b_ih0 + b_hh0   (M=32768, K=256)
  gemm_xproj<<<dim3(256, 4), 256, 0, stream>>>(xf16, Wih0, b_ih0, b_hh0, xproj, DIN_);
  // 3) layer-0 scan -> h1seq   (128 WGs = 2 per batch element)
  rnn_scan<<<128, 512, 0, stream>>>((const uint4*)Ws0, xproj, h1seq, h2, hglob, flg0, 0);
  // 4) xproj1 = h1seq @ w_ih1^T + b_ih1 + b_hh1   (M=32768, K=512)
  gemm_xproj<<<dim3(256, 4), 256, 0, stream>>>(h1seq, Wih1, b_ih1, b_hh1, xproj, H_);
  // 5) layer-1 scan -> h2 (fp32 final hidden only)
  rnn_scan<<<128, 512, 0, stream>>>((const uint4*)Ws1, xproj, h1seq, h2, hglob, flg1, 1);
  // 6) FC -> d_out (fp32, 64x128)
  fc_kernel<<<B_, DOUT_, 0, stream>>>(h2, w_fc, b_fc, (float*)d_out);
}

// Round 6
// 5050.134 us; speedup vs baseline: 1.7696x; 1.7696x over previous
//
#include <hip/hip_runtime.h>

// Problem dims (fp32 in / fp32 out)
#define B_   64
#define T_   512
#define DIN_ 256
#define H_   512
#define DOUT_ 128

typedef _Float16 f16x8 __attribute__((ext_vector_type(8)));
typedef float f32x4  __attribute__((ext_vector_type(4)));
typedef _Float16 half2v __attribute__((ext_vector_type(2)));

// ---------------------------------------------------------------------------
// dot of 8 f16 pairs (w,h packed as uint4) accumulated into fp32
__device__ __forceinline__ float dot8(uint4 w, uint4 h, float s) {
#if __has_builtin(__builtin_amdgcn_fdot2)
  s = __builtin_amdgcn_fdot2(__builtin_bit_cast(half2v, w.x), __builtin_bit_cast(half2v, h.x), s, false);
  s = __builtin_amdgcn_fdot2(__builtin_bit_cast(half2v, w.y), __builtin_bit_cast(half2v, h.y), s, false);
  s = __builtin_amdgcn_fdot2(__builtin_bit_cast(half2v, w.z), __builtin_bit_cast(half2v, h.z), s, false);
  s = __builtin_amdgcn_fdot2(__builtin_bit_cast(half2v, w.w), __builtin_bit_cast(half2v, h.w), s, false);
#else
  const half2v* wp = (const half2v*)&w;
  const half2v* hp = (const half2v*)&h;
#pragma unroll
  for (int q = 0; q < 4; ++q) {
    s += (float)wp[q][0] * (float)hp[q][0] + (float)wp[q][1] * (float)hp[q][1];
  }
#endif
  return s;
}

// fast branchless tanh: tanh(x) = sign(x) * (1 - 2/(e^{2|x|}+1)); |err| ~1e-6
__device__ __forceinline__ float fast_tanh(float x) {
  float a = fabsf(x);
  float e = __expf(2.f * a);
  float r = 1.f - 2.f / (e + 1.f);
  return copysignf(r, x);
}

// opaque pin: forces v's components into arch VGPRs at this point and makes
// the producing loads non-rematerializable
__device__ __forceinline__ void pin4(uint4& v) {
  asm volatile("" : "+v"(v.x), "+v"(v.y), "+v"(v.z), "+v"(v.w));
}

// ---------------------------------------------------------------------------
// Generic fp32 -> f16 conversion (memory-bound, one-shot prep)
__global__ void cvt_f32_f16(const float* __restrict__ in, _Float16* __restrict__ out, int n) {
  int idx = blockIdx.x * 256 + threadIdx.x;
  if (idx < n) out[idx] = (_Float16)in[idx];
}

// ---------------------------------------------------------------------------
// Prep: convert W_hh (fp32, row-major HxH) into the scan's layout:
//   chunk c = (rsub*16 + i)*512 + tid   holds  W[4*(tid&127)+rsub][(tid>>7)*128 + i*8 .. +8)
// (tid = scan thread 0..511, rsub = which of the thread's 4 rows, i = k-chunk
//  within the thread's k-quarter). Scan loads chunk (rsub,i) at lane-stride
//  16 B -> fully coalesced, both for the register fill and per-step streaming.
__global__ void prep_w(const float* __restrict__ w0, const float* __restrict__ w1,
                       _Float16* __restrict__ o0, _Float16* __restrict__ o1) {
  int idx = blockIdx.x * 256 + threadIdx.x;        // 0 .. 65535 (two matrices)
  const float* src = (idx < 32768) ? w0 : w1;
  _Float16* dst = (idx < 32768) ? o0 : o1;
  int c = idx & 32767;
  int tid  = c & 511;
  int rest = c >> 9;          // 0..63
  int i    = rest & 15;
  int rsub = rest >> 4;       // 0..3
  int row = 4 * (tid & 127) + rsub;
  int kc  = (tid >> 7) * 16 + i;
#pragma unroll
  for (int e = 0; e < 8; ++e)
    dst[(size_t)c * 8 + e] = (_Float16)src[row * 512 + kc * 8 + e];
}

// ---------------------------------------------------------------------------
// GEMM: out[m,n] = sum_k X[m,k]*W[n,k] + bias1[n] + bias2[n], written as f16.
// 128x128 tile / 256 threads / 4 waves (2x2 of 64x64), BK=32, m97-style
// global_load_lds(16B) staging, 16x16x32 f16 MFMA.  (unchanged — ~40 us)
__global__ __launch_bounds__(256)
void gemm_xproj(const _Float16* __restrict__ X,
                const _Float16* __restrict__ W,
                const float* __restrict__ bias1,
                const float* __restrict__ bias2,
                _Float16* __restrict__ out, int K) {
  __shared__ __align__(16) _Float16 As[128 * 32];
  __shared__ __align__(16) _Float16 Bs[128 * 32];
  const int tid  = threadIdx.x;
  const int wave = tid >> 6;
  const int lane = tid & 63;
  const int wr = wave >> 1, wc = wave & 1;
  const int m0 = blockIdx.x * 128, n0 = blockIdx.y * 128;
  const int fr = lane & 15;
  const int fk = (lane >> 4) * 8;
  const int cA = (lane & 3) * 8;
  const int rsub = lane >> 2;

  f32x4 acc[4][4];
#pragma unroll
  for (int a = 0; a < 4; ++a)
#pragma unroll
    for (int b = 0; b < 4; ++b)
      acc[a][b] = (f32x4){0.f, 0.f, 0.f, 0.f};

  for (int k0 = 0; k0 < K; k0 += 32) {
    __syncthreads();
#pragma unroll
    for (int q = 0; q < 2; ++q) {
      int p = wave * 2 + q;
      int r = p * 16 + rsub;
      const _Float16* gA = X + (size_t)(m0 + r) * K + (k0 + cA);
      const _Float16* gB = W + (size_t)(n0 + r) * K + (k0 + cA);
      __builtin_amdgcn_global_load_lds(
          (const __attribute__((address_space(1))) void*)gA,
          (__attribute__((address_space(3))) void*)((char*)As + p * 1024), 16, 0, 0);
      __builtin_amdgcn_global_load_lds(
          (const __attribute__((address_space(1))) void*)gB,
          (__attribute__((address_space(3))) void*)((char*)Bs + p * 1024), 16, 0, 0);
    }
    __syncthreads();

    f16x8 af[4], bfr[4];
#pragma unroll
    for (int mt = 0; mt < 4; ++mt)
      af[mt] = *(const f16x8*)&As[(wr * 64 + mt * 16 + fr) * 32 + fk];
#pragma unroll
    for (int nt = 0; nt < 4; ++nt)
      bfr[nt] = *(const f16x8*)&Bs[(wc * 64 + nt * 16 + fr) * 32 + fk];
#pragma unroll
    for (int mt = 0; mt < 4; ++mt)
#pragma unroll
      for (int nt = 0; nt < 4; ++nt)
        acc[mt][nt] = __builtin_amdgcn_mfma_f32_16x16x32_f16(af[mt], bfr[nt], acc[mt][nt], 0, 0, 0);
  }

  const int col = lane & 15, rq = lane >> 4;
#pragma unroll
  for (int nt = 0; nt < 4; ++nt) {
    int n = n0 + wc * 64 + nt * 16 + col;
    float bias = bias1[n] + bias2[n];
#pragma unroll
    for (int mt = 0; mt < 4; ++mt) {
      int mbase = m0 + wr * 64 + mt * 16 + rq * 4;
#pragma unroll
      for (int r = 0; r < 4; ++r)
        out[(size_t)(mbase + r) * H_ + n] = (_Float16)(acc[mt][nt][r] + bias);
    }
  }
}

// ---------------------------------------------------------------------------
// Recurrent scan, round-6: one WG per batch element (64 WGs, NO cross-WG sync
// — r5 lesson: per-step global handshakes cost us-scale). 512 threads =
// 128 row-groups x 4 k-quarters; thread (r,u) computes rows {4r..4r+3} over
// k-quarter u. This cuts per-thread h-chunk LDS reads 64 -> 16 (the r3 wall:
// LDS h-insts = 6144/R cyc; R=4 -> 1536). W rows 0..2 register-resident
// (48 uint4 = 192 VGPR; AGPR demotion OK), row 3 streamed from L2 per step
// (131 KB/step/CU, same data for all WGs -> L2-hot; global pipe overlaps LDS
// pipe) via an 8-deep prefetch ring. Partials reduced through 8 KB LDS psum.
__global__ __launch_bounds__(512, 2)
void rnn_scan(const uint4* __restrict__ Wg, const _Float16* __restrict__ xproj,
              _Float16* __restrict__ seq, float* __restrict__ hlast, int mode) {
  __shared__ __align__(16) _Float16 hb[2][512];   // h double buffer (2 KB)
  __shared__ __align__(16) float psum[4][512];    // k-quarter partials (8 KB)
  const int b = blockIdx.x;
  const int tid = threadIdx.x;
  const int r = tid & 127, u = tid >> 7;
  (void)r;

  // register-resident W rows 0..2 (lane-coalesced: consecutive tid = 16 B apart)
  uint4 w0[16], w1[16], w2[16];
#pragma unroll
  for (int i = 0; i < 16; ++i) {
    w0[i] = Wg[(0 * 16 + i) * 512 + tid];
    w1[i] = Wg[(1 * 16 + i) * 512 + tid];
    w2[i] = Wg[(2 * 16 + i) * 512 + tid];
  }
#pragma unroll
  for (int i = 0; i < 16; ++i) { pin4(w0[i]); pin4(w1[i]); pin4(w2[i]); }

  hb[0][tid] = (_Float16)0.f;
  hb[1][tid] = (_Float16)0.f;
  __syncthreads();

  const uint4* w3p = Wg + (size_t)48 * 512 + tid;   // streamed row 3, loop-invariant
  const _Float16* xp = xproj + (size_t)b * (T_ * H_) + tid;
  _Float16* sq = seq + (size_t)b * (T_ * H_) + tid;
  int cur = 0;
  for (int t = 0; t < T_; ++t) {
    float xv = (float)xp[(size_t)t * H_];           // used after barrier A — latency hidden
    const uint4* hbu = (const uint4*)hb[cur] + u * 16;

    uint4 q[8];                                     // prefetch ring for streamed row 3
#pragma unroll
    for (int i = 0; i < 8; ++i) q[i] = w3p[(size_t)i * 512];

    float a0 = 0.f, a1 = 0.f, a2 = 0.f, a3 = 0.f;
#pragma unroll
    for (int i = 0; i < 16; ++i) {
      uint4 h = hbu[i];
      a0 = dot8(w0[i], h, a0);
      a1 = dot8(w1[i], h, a1);
      a2 = dot8(w2[i], h, a2);
      a3 = dot8(q[i & 7], h, a3);
      if (i + 8 < 16) q[i & 7] = w3p[(size_t)(i + 8) * 512];
    }
    // psum[u][4r+rsub]: contiguous 16 B per thread -> single b128, conflict-free
    *(f32x4*)&psum[u][4 * (tid & 127)] = (f32x4){a0, a1, a2, a3};
    __syncthreads();                                // A: partials visible

    // reduce: thread t owns row t (psum[u][t] reads are lane-stride 4 B)
    float s = (psum[0][tid] + psum[1][tid]) + (psum[2][tid] + psum[3][tid]);
    float hn = fast_tanh(s + xv);
    _Float16 h16 = (_Float16)hn;
    hb[cur ^ 1][tid] = h16;
    if (mode == 0) {
      sq[(size_t)t * H_] = h16;
    } else if (t == T_ - 1) {
      hlast[b * H_ + tid] = hn;
    }
    __syncthreads();                                // B: hb[cur^1] complete
    cur ^= 1;
  }
}

// ---------------------------------------------------------------------------
// Final FC: out[b,o] = h2[b,:] . w_fc[o,:] + b_fc[o]   (64 x 128, tiny, pure fp32)
__global__ void fc_kernel(const float* __restrict__ h2,
                          const float* __restrict__ wfc,
                          const float* __restrict__ bfc,
                          float* __restrict__ out) {
  int b = blockIdx.x, o = threadIdx.x;
  float s = bfc[o];
  const float* hv = h2 + b * H_;
  const float* wr = wfc + (size_t)o * H_;
#pragma unroll 8
  for (int k = 0; k < H_; ++k) s += hv[k] * wr[k];
  out[b * DOUT_ + o] = s;
}

// ---------------------------------------------------------------------------
extern "C" void kernel_launch(void* const* d_in, const int* in_sizes, int n_in,
                              void* d_out, int out_size, void* d_ws, size_t ws_size,
                              hipStream_t stream) {
  const float* x     = (const float*)d_in[0];
  const float* w_ih0 = (const float*)d_in[1];
  const float* w_hh0 = (const float*)d_in[2];
  const float* b_ih0 = (const float*)d_in[3];
  const float* b_hh0 = (const float*)d_in[4];
  const float* w_ih1 = (const float*)d_in[5];
  const float* w_hh1 = (const float*)d_in[6];
  const float* b_ih1 = (const float*)d_in[7];
  const float* b_hh1 = (const float*)d_in[8];
  const float* w_fc  = (const float*)d_in[9];
  const float* b_fc  = (const float*)d_in[10];

  char* ws = (char*)d_ws;
  _Float16* Ws0   = (_Float16*)(ws + 0);          // 512 KB  (w_hh0 scan layout)
  _Float16* Ws1   = (_Float16*)(ws + 524288);     // 512 KB  (w_hh1 scan layout)
  _Float16* Wih0  = (_Float16*)(ws + 1048576);    // 256 KB  (w_ih0 f16)
  _Float16* Wih1  = (_Float16*)(ws + 1310720);    // 512 KB  (w_ih1 f16)
  float*    h2    = (float*)   (ws + 2097152);    // 128 KB  (final hidden, fp32)
  _Float16* xproj = (_Float16*)(ws + 4194304);    // 32 MB   (32768x512 f16)
  _Float16* xf16  = (_Float16*)(ws + 37748736);   // x as f16, then dead...
  _Float16* h1seq = (_Float16*)(ws + 37748736);   // ...h1 sequence f16 (32 MB)

  // 1) one-shot conversions to f16
  cvt_f32_f16<<<32768, 256, 0, stream>>>(x, xf16, B_ * T_ * DIN_);
  cvt_f32_f16<<<512,   256, 0, stream>>>(w_ih0, Wih0, H_ * DIN_);
  cvt_f32_f16<<<1024,  256, 0, stream>>>(w_ih1, Wih1, H_ * H_);
  prep_w<<<256, 256, 0, stream>>>(w_hh0, w_hh1, Ws0, Ws1);

  // 2) xproj0 = x @ w_ih0^T + b_ih0 + b_hh0   (M=32768, K=256)
  gemm_xproj<<<dim3(256, 4), 256, 0, stream>>>(xf16, Wih0, b_ih0, b_hh0, xproj, DIN_);
  // 3) layer-0 scan -> h1seq
  rnn_scan<<<B_, 512, 0, stream>>>((const uint4*)Ws0, xproj, h1seq, h2, 0);
  // 4) xproj1 = h1seq @ w_ih1^T + b_ih1 + b_hh1   (M=32768, K=512)
  gemm_xproj<<<dim3(256, 4), 256, 0, stream>>>(h1seq, Wih1, b_ih1, b_hh1, xproj, H_);
  // 5) layer-1 scan -> h2 (fp32 final hidden only)
  rnn_scan<<<B_, 512, 0, stream>>>((const uint4*)Ws1, xproj, h1seq, h2, 1);
  // 6) FC -> d_out (fp32, 64x128)
  fc_kernel<<<B_, DOUT_, 0, stream>>>(h2, w_fc, b_fc, (float*)d_out);
}

// Round 7
// 1904.304 us; speedup vs baseline: 4.6928x; 2.6520x over previous
//
#include <hip/hip_runtime.h>

// Problem dims (fp32 in / fp32 out)
#define B_   64
#define T_   512
#define DIN_ 256
#define H_   512
#define DOUT_ 128

typedef _Float16 f16x8 __attribute__((ext_vector_type(8)));
typedef float f32x4  __attribute__((ext_vector_type(4)));
typedef _Float16 half2v __attribute__((ext_vector_type(2)));

// ---------------------------------------------------------------------------
// dot of 8 f16 pairs (w,h packed as uint4) accumulated into fp32
__device__ __forceinline__ float dot8(uint4 w, uint4 h, float s) {
#if __has_builtin(__builtin_amdgcn_fdot2)
  s = __builtin_amdgcn_fdot2(__builtin_bit_cast(half2v, w.x), __builtin_bit_cast(half2v, h.x), s, false);
  s = __builtin_amdgcn_fdot2(__builtin_bit_cast(half2v, w.y), __builtin_bit_cast(half2v, h.y), s, false);
  s = __builtin_amdgcn_fdot2(__builtin_bit_cast(half2v, w.z), __builtin_bit_cast(half2v, h.z), s, false);
  s = __builtin_amdgcn_fdot2(__builtin_bit_cast(half2v, w.w), __builtin_bit_cast(half2v, h.w), s, false);
#else
  const half2v* wp = (const half2v*)&w;
  const half2v* hp = (const half2v*)&h;
#pragma unroll
  for (int q = 0; q < 4; ++q) {
    s += (float)wp[q][0] * (float)hp[q][0] + (float)wp[q][1] * (float)hp[q][1];
  }
#endif
  return s;
}

// fast branchless tanh: tanh(x) = sign(x) * (1 - 2/(e^{2|x|}+1)); |err| ~1e-6
__device__ __forceinline__ float fast_tanh(float x) {
  float a = fabsf(x);
  float e = __expf(2.f * a);
  float r = 1.f - 2.f / (e + 1.f);
  return copysignf(r, x);
}

// opaque pin: forces v's components into arch VGPRs at this point and makes
// the producing loads non-rematerializable
__device__ __forceinline__ void pin4(uint4& v) {
  asm volatile("" : "+v"(v.x), "+v"(v.y), "+v"(v.z), "+v"(v.w));
}

// ---------------------------------------------------------------------------
// Generic fp32 -> f16 conversion (memory-bound, one-shot prep)
__global__ void cvt_f32_f16(const float* __restrict__ in, _Float16* __restrict__ out, int n) {
  int idx = blockIdx.x * 256 + threadIdx.x;
  if (idx < n) out[idx] = (_Float16)in[idx];
}

// ---------------------------------------------------------------------------
// Prep: convert W_hh (fp32, row-major HxH) into the scan's layout (as r6):
//   chunk c = (rsub*16 + i)*512 + tid   holds  W[4*(tid&127)+rsub][(tid>>7)*128 + i*8 .. +8)
// Scan thread tid loads chunk (rsub,i) at lane-stride 16 B -> fully coalesced.
__global__ void prep_w(const float* __restrict__ w0, const float* __restrict__ w1,
                       _Float16* __restrict__ o0, _Float16* __restrict__ o1) {
  int idx = blockIdx.x * 256 + threadIdx.x;        // 0 .. 65535 (two matrices)
  const float* src = (idx < 32768) ? w0 : w1;
  _Float16* dst = (idx < 32768) ? o0 : o1;
  int c = idx & 32767;
  int tid  = c & 511;
  int rest = c >> 9;          // 0..63
  int i    = rest & 15;
  int rsub = rest >> 4;       // 0..3
  int row = 4 * (tid & 127) + rsub;
  int kc  = (tid >> 7) * 16 + i;
#pragma unroll
  for (int e = 0; e < 8; ++e)
    dst[(size_t)c * 8 + e] = (_Float16)src[row * 512 + kc * 8 + e];
}

// ---------------------------------------------------------------------------
// GEMM: out[m,n] = sum_k X[m,k]*W[n,k] + bias1[n] + bias2[n], written as f16.
// 128x128 tile / 256 threads / 4 waves (2x2 of 64x64), BK=32, m97-style
// global_load_lds(16B) staging, 16x16x32 f16 MFMA.  (unchanged — ~40 us)
__global__ __launch_bounds__(256)
void gemm_xproj(const _Float16* __restrict__ X,
                const _Float16* __restrict__ W,
                const float* __restrict__ bias1,
                const float* __restrict__ bias2,
                _Float16* __restrict__ out, int K) {
  __shared__ __align__(16) _Float16 As[128 * 32];
  __shared__ __align__(16) _Float16 Bs[128 * 32];
  const int tid  = threadIdx.x;
  const int wave = tid >> 6;
  const int lane = tid & 63;
  const int wr = wave >> 1, wc = wave & 1;
  const int m0 = blockIdx.x * 128, n0 = blockIdx.y * 128;
  const int fr = lane & 15;
  const int fk = (lane >> 4) * 8;
  const int cA = (lane & 3) * 8;
  const int rsub = lane >> 2;

  f32x4 acc[4][4];
#pragma unroll
  for (int a = 0; a < 4; ++a)
#pragma unroll
    for (int b = 0; b < 4; ++b)
      acc[a][b] = (f32x4){0.f, 0.f, 0.f, 0.f};

  for (int k0 = 0; k0 < K; k0 += 32) {
    __syncthreads();
#pragma unroll
    for (int q = 0; q < 2; ++q) {
      int p = wave * 2 + q;
      int r = p * 16 + rsub;
      const _Float16* gA = X + (size_t)(m0 + r) * K + (k0 + cA);
      const _Float16* gB = W + (size_t)(n0 + r) * K + (k0 + cA);
      __builtin_amdgcn_global_load_lds(
          (const __attribute__((address_space(1))) void*)gA,
          (__attribute__((address_space(3))) void*)((char*)As + p * 1024), 16, 0, 0);
      __builtin_amdgcn_global_load_lds(
          (const __attribute__((address_space(1))) void*)gB,
          (__attribute__((address_space(3))) void*)((char*)Bs + p * 1024), 16, 0, 0);
    }
    __syncthreads();

    f16x8 af[4], bfr[4];
#pragma unroll
    for (int mt = 0; mt < 4; ++mt)
      af[mt] = *(const f16x8*)&As[(wr * 64 + mt * 16 + fr) * 32 + fk];
#pragma unroll
    for (int nt = 0; nt < 4; ++nt)
      bfr[nt] = *(const f16x8*)&Bs[(wc * 64 + nt * 16 + fr) * 32 + fk];
#pragma unroll
    for (int mt = 0; mt < 4; ++mt)
#pragma unroll
      for (int nt = 0; nt < 4; ++nt)
        acc[mt][nt] = __builtin_amdgcn_mfma_f32_16x16x32_f16(af[mt], bfr[nt], acc[mt][nt], 0, 0, 0);
  }

  const int col = lane & 15, rq = lane >> 4;
#pragma unroll
  for (int nt = 0; nt < 4; ++nt) {
    int n = n0 + wc * 64 + nt * 16 + col;
    float bias = bias1[n] + bias2[n];
#pragma unroll
    for (int mt = 0; mt < 4; ++mt) {
      int mbase = m0 + wr * 64 + mt * 16 + rq * 4;
#pragma unroll
      for (int r = 0; r < 4; ++r)
        out[(size_t)(mbase + r) * H_ + n] = (_Float16)(acc[mt][nt][r] + bias);
    }
  }
}

// ---------------------------------------------------------------------------
// Recurrent scan, round-7: one WG per batch element (64 WGs, no cross-WG sync).
// 512 threads = 128 row-groups x 4 k-quarters; thread (r=tid&127, u=tid>>7)
// computes rows {4r..4r+3} over k-quarter u (16 h-chunks/thread -> h-broadcast
// LDS cost 1536 cyc/step, the r6-verified fix of the r3 wall).
// W delivery split across three CONCURRENT pipes (r6 lesson: >64 pinned VGPRs
// spill to scratch; keep register ambition modest):
//   slots  0..15 (row+0)        -> 16 uint4 = 64 VGPR register-resident
//   slots 16..21 (row+1,i<6)    -> 48 KB LDS-resident (r2-proven path)
//   slots 22..63 (rest)         -> streamed from L2 (336 KB/step/CU ~1500 cyc
//                                  at ~225 B/cyc/CU), three 4-deep prefetch rings
// Per-step model: LDS ~1530 cyc || L2 ~1500 cyc || VALU ~1100 cyc -> ~2.2k cyc.
__global__ __launch_bounds__(512, 2)
void rnn_scan(const uint4* __restrict__ Wg, const _Float16* __restrict__ xproj,
              _Float16* __restrict__ seq, float* __restrict__ hlast, int mode) {
  __shared__ __align__(16) uint4 ldsW[6 * 512];     // 48 KB (slots 16..21)
  __shared__ __align__(16) _Float16 hb[2][512];     // h double buffer (2 KB)
  __shared__ __align__(16) float psum[4][512];      // k-quarter partials (8 KB)
  const int b = blockIdx.x;
  const int tid = threadIdx.x;
  const int u = tid >> 7;                           // k-quarter 0..3

  // slots 0..15 (thread's row+0) -> 64 VGPRs, coalesced (lane stride 16 B)
  uint4 wreg[16];
#pragma unroll
  for (int i = 0; i < 16; ++i) wreg[i] = Wg[i * 512 + tid];
#pragma unroll
  for (int i = 0; i < 16; ++i) pin4(wreg[i]);

  // slots 16..21 -> LDS
#pragma unroll
  for (int i = 0; i < 6; ++i) ldsW[i * 512 + tid] = Wg[(16 + i) * 512 + tid];

  hb[0][tid] = (_Float16)0.f;
  hb[1][tid] = (_Float16)0.f;
  __syncthreads();

  const uint4* S1 = Wg + (size_t)22 * 512 + tid;    // row+1, i=6..15 (10 slots)
  const uint4* S2 = Wg + (size_t)32 * 512 + tid;    // row+2, i=0..15 (16 slots)
  const uint4* S3 = Wg + (size_t)48 * 512 + tid;    // row+3, i=0..15 (16 slots)
  const _Float16* xp = xproj + (size_t)b * (T_ * H_) + tid;
  _Float16* sq = seq + (size_t)b * (T_ * H_) + tid;

  int cur = 0;
  for (int t = 0; t < T_; ++t) {
    float xv = (float)xp[(size_t)t * H_];           // consumed after barrier A
    const uint4* hbu = (const uint4*)hb[cur] + u * 16;

    // prefill the three 4-deep rings (12 outstanding loads, ~350 cyc of cover)
    uint4 q1[4], q2[4], q3[4];
#pragma unroll
    for (int p = 0; p < 4; ++p) {
      q1[p] = S1[(size_t)p * 512];
      q2[p] = S2[(size_t)p * 512];
      q3[p] = S3[(size_t)p * 512];
    }

    float a0 = 0.f, a1 = 0.f, a2 = 0.f, a3 = 0.f;   // row accumulators = 4 chains
#pragma unroll
    for (int i = 0; i < 16; ++i) {
      uint4 h = hbu[i];                             // one b128 broadcast read
      a0 = dot8(wreg[i], h, a0);
      if (i < 6) {
        a1 = dot8(ldsW[i * 512 + tid], h, a1);
      } else {
        a1 = dot8(q1[(i - 6) & 3], h, a1);
        if (i - 6 + 4 < 10) q1[(i - 6) & 3] = S1[(size_t)(i - 2) * 512];
      }
      a2 = dot8(q2[i & 3], h, a2);
      if (i + 4 < 16) q2[i & 3] = S2[(size_t)(i + 4) * 512];
      a3 = dot8(q3[i & 3], h, a3);
      if (i + 4 < 16) q3[i & 3] = S3[(size_t)(i + 4) * 512];
    }
    // psum[u][4r+rsub]: one contiguous b128 per thread, conflict-free
    *(f32x4*)&psum[u][4 * (tid & 127)] = (f32x4){a0, a1, a2, a3};
    __syncthreads();                                // A: partials visible

    // reduce: thread tid owns row tid (lane-stride-4B reads, conflict-free)
    float s = (psum[0][tid] + psum[1][tid]) + (psum[2][tid] + psum[3][tid]);
    float hn = fast_tanh(s + xv);
    _Float16 h16 = (_Float16)hn;
    hb[cur ^ 1][tid] = h16;
    if (mode == 0) {
      sq[(size_t)t * H_] = h16;
    } else if (t == T_ - 1) {
      hlast[b * H_ + tid] = hn;
    }
    __syncthreads();                                // B: hb[cur^1] complete
    cur ^= 1;
  }
}

// ---------------------------------------------------------------------------
// Final FC: out[b,o] = h2[b,:] . w_fc[o,:] + b_fc[o]   (64 x 128, tiny, pure fp32)
__global__ void fc_kernel(const float* __restrict__ h2,
                          const float* __restrict__ wfc,
                          const float* __restrict__ bfc,
                          float* __restrict__ out) {
  int b = blockIdx.x, o = threadIdx.x;
  float s = bfc[o];
  const float* hv = h2 + b * H_;
  const float* wr = wfc + (size_t)o * H_;
#pragma unroll 8
  for (int k = 0; k < H_; ++k) s += hv[k] * wr[k];
  out[b * DOUT_ + o] = s;
}

// ---------------------------------------------------------------------------
extern "C" void kernel_launch(void* const* d_in, const int* in_sizes, int n_in,
                              void* d_out, int out_size, void* d_ws, size_t ws_size,
                              hipStream_t stream) {
  const float* x     = (const float*)d_in[0];
  const float* w_ih0 = (const float*)d_in[1];
  const float* w_hh0 = (const float*)d_in[2];
  const float* b_ih0 = (const float*)d_in[3];
  const float* b_hh0 = (const float*)d_in[4];
  const float* w_ih1 = (const float*)d_in[5];
  const float* w_hh1 = (const float*)d_in[6];
  const float* b_ih1 = (const float*)d_in[7];
  const float* b_hh1 = (const float*)d_in[8];
  const float* w_fc  = (const float*)d_in[9];
  const float* b_fc  = (const float*)d_in[10];

  char* ws = (char*)d_ws;
  _Float16* Ws0   = (_Float16*)(ws + 0);          // 512 KB  (w_hh0 scan layout)
  _Float16* Ws1   = (_Float16*)(ws + 524288);     // 512 KB  (w_hh1 scan layout)
  _Float16* Wih0  = (_Float16*)(ws + 1048576);    // 256 KB  (w_ih0 f16)
  _Float16* Wih1  = (_Float16*)(ws + 1310720);    // 512 KB  (w_ih1 f16)
  float*    h2    = (float*)   (ws + 2097152);    // 128 KB  (final hidden, fp32)
  _Float16* xproj = (_Float16*)(ws + 4194304);    // 32 MB   (32768x512 f16)
  _Float16* xf16  = (_Float16*)(ws + 37748736);   // x as f16, then dead...
  _Float16* h1seq = (_Float16*)(ws + 37748736);   // ...h1 sequence f16 (32 MB)

  // 1) one-shot conversions to f16
  cvt_f32_f16<<<32768, 256, 0, stream>>>(x, xf16, B_ * T_ * DIN_);
  cvt_f32_f16<<<512,   256, 0, stream>>>(w_ih0, Wih0, H_ * DIN_);
  cvt_f32_f16<<<1024,  256, 0, stream>>>(w_ih1, Wih1, H_ * H_);
  prep_w<<<256, 256, 0, stream>>>(w_hh0, w_hh1, Ws0, Ws1);

  // 2) xproj0 = x @ w_ih0^T + b_ih0 + b_hh0   (M=32768, K=256)
  gemm_xproj<<<dim3(256, 4), 256, 0, stream>>>(xf16, Wih0, b_ih0, b_hh0, xproj, DIN_);
  // 3) layer-0 scan -> h1seq
  rnn_scan<<<B_, 512, 0, stream>>>((const uint4*)Ws0, xproj, h1seq, h2, 0);
  // 4) xproj1 = h1seq @ w_ih1^T + b_ih1 + b_hh1   (M=32768, K=512)
  gemm_xproj<<<dim3(256, 4), 256, 0, stream>>>(h1seq, Wih1, b_ih1, b_hh1, xproj, H_);
  // 5) layer-1 scan -> h2 (fp32 final hidden only)
  rnn_scan<<<B_, 512, 0, stream>>>((const uint4*)Ws1, xproj, h1seq, h2, 1);
  // 6) FC -> d_out (fp32, 64x128)
  fc_kernel<<<B_, DOUT_, 0, stream>>>(h2, w_fc, b_fc, (float*)d_out);
}